// Round 1
// baseline (990.359 us; speedup 1.0000x reference)
//
#include <hip/hip_runtime.h>
#include <hip/hip_bf16.h>

#define DIM 768
#define SLEN 4096
#define BATCH 4

typedef __attribute__((ext_vector_type(8))) short short8;
typedef __attribute__((ext_vector_type(4))) short short4v;
typedef __attribute__((ext_vector_type(4))) float f32x4;
typedef __attribute__((ext_vector_type(8))) __bf16 bf16x8;

__device__ __forceinline__ unsigned short f2bf(float x) {
  union { float f; unsigned u; } c; c.f = x;
  return (unsigned short)((c.u + 0x7fffu + ((c.u >> 16) & 1u)) >> 16);
}

union V8 { short8 v; unsigned short u[8]; };

// ---------------- kernel 1: x fp32 -> bf16 ----------------
__global__ __launch_bounds__(256) void convert_x_kernel(
    const float* __restrict__ x, unsigned short* __restrict__ xb) {
  size_t i = ((size_t)blockIdx.x * 256 + threadIdx.x) * 8;
  f32x4 a = *(const f32x4*)(x + i);
  f32x4 b = *(const f32x4*)(x + i + 4);
  V8 o;
#pragma unroll
  for (int j = 0; j < 4; ++j) { o.u[j] = f2bf(a[j]); o.u[4 + j] = f2bf(b[j]); }
  *(short8*)(xb + i) = o.v;
}

// ---------------- kernel 2: W [k][n] fp32 -> Wt [n][k] bf16 ----------------
__global__ __launch_bounds__(256) void transpose_w_kernel(
    const float* __restrict__ Wq, const float* __restrict__ Wk,
    const float* __restrict__ Wv, unsigned short* __restrict__ Wt) {
  __shared__ float Tl[32][33];
  const float* Wi = blockIdx.z == 0 ? Wq : (blockIdx.z == 1 ? Wk : Wv);
  unsigned short* Wo = Wt + (size_t)blockIdx.z * DIM * DIM;
  int k0 = blockIdx.x * 32, n0 = blockIdx.y * 32;
  int t = threadIdx.x;
  int r = t >> 3, c4 = (t & 7) * 4;
  f32x4 v = *(const f32x4*)(Wi + (size_t)(k0 + r) * DIM + n0 + c4);
#pragma unroll
  for (int j = 0; j < 4; ++j) Tl[r][c4 + j] = v[j];
  __syncthreads();
  short4v ov;
#pragma unroll
  for (int j = 0; j < 4; ++j) ov[j] = (short)f2bf(Tl[c4 + j][r]);
  *(short4v*)(Wo + (size_t)(n0 + r) * DIM + k0 + c4) = ov;
}

// ---------------- kernel 3: QKV GEMM (bf16 MFMA) ----------------
// out[m][n] = sum_k xb[m][k] * W[k][n],  W read via Wt[n][k].
__global__ __launch_bounds__(256) void qkv_gemm_kernel(
    const unsigned short* __restrict__ xb, const unsigned short* __restrict__ wt,
    unsigned short* __restrict__ Qo, unsigned short* __restrict__ Ko,
    unsigned short* __restrict__ Vo) {
  __shared__ __align__(16) unsigned short As[64 * 40];
  __shared__ __align__(16) unsigned short Bs[3][64 * 40];
  const int t = threadIdx.x;
  const int lane = t & 63, w = t >> 6;
  const int l15 = lane & 15, lg = lane >> 4;
  const int wm = w >> 1, wn = w & 1;
  const int m0 = blockIdx.x * 64, n0 = blockIdx.y * 64;
  f32x4 acc[3][2][2];
#pragma unroll
  for (int i = 0; i < 3; ++i)
#pragma unroll
    for (int a = 0; a < 2; ++a)
#pragma unroll
      for (int b = 0; b < 2; ++b) acc[i][a][b] = f32x4{0.f, 0.f, 0.f, 0.f};
  const int arow = t >> 2, koff = (t & 3) * 8;

  for (int kb = 0; kb < DIM; kb += 32) {
    __syncthreads();
    *(short8*)(As + arow * 40 + koff) =
        *(const short8*)(xb + (size_t)(m0 + arow) * DIM + kb + koff);
#pragma unroll
    for (int i = 0; i < 3; ++i)
      *(short8*)(&Bs[i][arow * 40 + koff]) =
          *(const short8*)(wt + (size_t)i * DIM * DIM + (size_t)(n0 + arow) * DIM + kb + koff);
    __syncthreads();
    bf16x8 a[2];
#pragma unroll
    for (int mi = 0; mi < 2; ++mi)
      a[mi] = __builtin_bit_cast(
          bf16x8, *(const short8*)(As + (wm * 32 + mi * 16 + l15) * 40 + lg * 8));
#pragma unroll
    for (int i = 0; i < 3; ++i) {
#pragma unroll
      for (int ni = 0; ni < 2; ++ni) {
        bf16x8 bv = __builtin_bit_cast(
            bf16x8, *(const short8*)(&Bs[i][(wn * 32 + ni * 16 + l15) * 40 + lg * 8]));
#pragma unroll
        for (int mi = 0; mi < 2; ++mi)
          acc[i][mi][ni] =
              __builtin_amdgcn_mfma_f32_16x16x32_bf16(a[mi], bv, acc[i][mi][ni], 0, 0, 0);
      }
    }
  }
  unsigned short* outs[3] = {Qo, Ko, Vo};
#pragma unroll
  for (int i = 0; i < 3; ++i)
#pragma unroll
    for (int mi = 0; mi < 2; ++mi)
#pragma unroll
      for (int ni = 0; ni < 2; ++ni)
#pragma unroll
        for (int ii = 0; ii < 4; ++ii) {
          int row = m0 + wm * 32 + mi * 16 + lg * 4 + ii;
          int col = n0 + wn * 32 + ni * 16 + l15;
          outs[i][(size_t)row * DIM + col] = f2bf(acc[i][mi][ni][ii]);
        }
}

// ---------------- kernel 4: causal flash attention ----------------
// QBLK=32, KBLK=32, 4 waves. Q/K/Vt all LDS-resident. log2-domain softmax.
__global__ __launch_bounds__(256, 1) void attn_kernel(
    const unsigned short* __restrict__ Qg, const unsigned short* __restrict__ Kg,
    const unsigned short* __restrict__ Vg, float* __restrict__ Og) {
  __shared__ __align__(16) unsigned short Qs[32 * 768];
  __shared__ __align__(16) unsigned short Ks[32 * 768];
  __shared__ __align__(16) unsigned short Vts[768 * 32];
  __shared__ __align__(16) float Ss[32 * 33];
  __shared__ __align__(16) unsigned short Ps[32 * 40];
  __shared__ float m_s[32], l_s[32], al_s[32];

  const int t = threadIdx.x;
  const int lane = t & 63, w = t >> 6;
  const int l15 = lane & 15, lg = lane >> 4;
  const int b = blockIdx.y;
  const int qb = (int)(SLEN / 32 - 1) - (int)blockIdx.x;  // reverse order: big blocks first
  const unsigned short* Qp = Qg + ((size_t)b * SLEN + (size_t)qb * 32) * DIM;
  const unsigned short* Kp = Kg + (size_t)b * SLEN * DIM;
  const unsigned short* Vp = Vg + (size_t)b * SLEN * DIM;
  float* Op = Og + ((size_t)b * SLEN + (size_t)qb * 32) * DIM;

  // stage Q: 32x768 bf16, 16B-chunk swizzle (chunk ^ (row&7))
#pragma unroll
  for (int it = 0; it < 12; ++it) {
    int cid = t + it * 256;
    int r = cid / 96;
    int off = cid - r * 96;
    short8 v = *(const short8*)(Qp + (size_t)r * DIM + off * 8);
    *(short8*)(Qs + r * DIM + (off ^ (r & 7)) * 8) = v;
  }
  if (t < 32) { m_s[t] = -3.0e38f; l_s[t] = 0.f; }

  f32x4 acc[24];
#pragma unroll
  for (int i = 0; i < 24; ++i) acc[i] = f32x4{0.f, 0.f, 0.f, 0.f};

  const int mh = w & 1;    // row half (QK and PV)
  const int nh = w >> 1;   // QK: col half; PV: e half
  const float scl = 1.4426950408889634f / 27.712812921102035f;  // log2(e)/sqrt(768)

  const int nt = qb + 1;
  for (int kt = 0; kt < nt; ++kt) {
    __syncthreads();  // protect Ks/Vts/Ss/Ps from previous iteration's readers
    const unsigned short* Kt = Kp + (size_t)kt * 32 * DIM;
    const unsigned short* Vt = Vp + (size_t)kt * 32 * DIM;
#pragma unroll
    for (int it = 0; it < 12; ++it) {
      int cid = t + it * 256;
      int r = cid / 96;
      int off = cid - r * 96;
      short8 v = *(const short8*)(Kt + (size_t)r * DIM + off * 8);
      *(short8*)(Ks + r * DIM + (off ^ (r & 7)) * 8) = v;
    }
    // V transpose-stage: element (kv=r, e) -> Vts[e*32 + ((r>>3)^(e&3))*8 + (r&7)]
#pragma unroll
    for (int it = 0; it < 12; ++it) {
      int cid = t + it * 256;
      int r = cid & 31;
      int e0 = (cid >> 5) * 8;
      V8 v; v.v = *(const short8*)(Vt + (size_t)r * DIM + e0);
#pragma unroll
      for (int j = 0; j < 8; ++j) {
        int e = e0 + j;
        Vts[e * 32 + (((r >> 3) ^ (e & 3)) * 8) + (r & 7)] = v.u[j];
      }
    }
    __syncthreads();

    // QK^T quadrant (mh, nh), accumulate over e=768
    f32x4 s = f32x4{0.f, 0.f, 0.f, 0.f};
    const int qr = mh * 16 + l15;
    const int kr = nh * 16 + l15;
#pragma unroll
    for (int ec = 0; ec < 24; ++ec) {
      int cb = ec * 4 + lg;
      bf16x8 a = __builtin_bit_cast(bf16x8, *(const short8*)(Qs + qr * DIM + (cb ^ (qr & 7)) * 8));
      bf16x8 bb = __builtin_bit_cast(bf16x8, *(const short8*)(Ks + kr * DIM + (cb ^ (kr & 7)) * 8));
      s = __builtin_amdgcn_mfma_f32_16x16x32_bf16(a, bb, s, 0, 0, 0);
    }
    int colg = kt * 32 + nh * 16 + l15;
#pragma unroll
    for (int i = 0; i < 4; ++i) {
      int rloc = mh * 16 + lg * 4 + i;
      int rowg = qb * 32 + rloc;
      float sv = s[i] * scl;
      if (colg > rowg) sv = -3.0e38f;
      Ss[rloc * 33 + nh * 16 + l15] = sv;
    }
    __syncthreads();

    // online softmax: 8 threads per row
    {
      int row = t >> 3, sub = t & 7;
      float sv[4];
#pragma unroll
      for (int j = 0; j < 4; ++j) sv[j] = Ss[row * 33 + sub * 4 + j];
      float mx = fmaxf(fmaxf(sv[0], sv[1]), fmaxf(sv[2], sv[3]));
      mx = fmaxf(mx, __shfl_xor(mx, 1));
      mx = fmaxf(mx, __shfl_xor(mx, 2));
      mx = fmaxf(mx, __shfl_xor(mx, 4));
      float mold = m_s[row];
      float mnew = fmaxf(mold, mx);
      float p[4], sum = 0.f;
#pragma unroll
      for (int j = 0; j < 4; ++j) { p[j] = exp2f(sv[j] - mnew); sum += p[j]; }
      sum += __shfl_xor(sum, 1);
      sum += __shfl_xor(sum, 2);
      sum += __shfl_xor(sum, 4);
      float alpha = exp2f(mold - mnew);
      if (sub == 0) {
        m_s[row] = mnew;
        l_s[row] = alpha * l_s[row] + sum;
        al_s[row] = alpha;
      }
      short4v pv;
#pragma unroll
      for (int j = 0; j < 4; ++j) pv[j] = (short)f2bf(p[j]);
      *(short4v*)(Ps + row * 40 + sub * 4) = pv;
    }
    __syncthreads();

    // rescale + PV: wave (mh, eh=nh) computes rows mh*16..+15, e-half nh*384..+383
    {
      float al[4];
#pragma unroll
      for (int i = 0; i < 4; ++i) al[i] = al_s[mh * 16 + lg * 4 + i];
#pragma unroll
      for (int n = 0; n < 24; ++n)
#pragma unroll
        for (int i = 0; i < 4; ++i) acc[n][i] *= al[i];
      bf16x8 pa = __builtin_bit_cast(bf16x8, *(const short8*)(Ps + (mh * 16 + l15) * 40 + lg * 8));
#pragma unroll
      for (int n = 0; n < 24; ++n) {
        int e = nh * 384 + n * 16 + l15;
        bf16x8 bv = __builtin_bit_cast(bf16x8, *(const short8*)(Vts + e * 32 + ((lg ^ (e & 3)) * 8)));
        acc[n] = __builtin_amdgcn_mfma_f32_16x16x32_bf16(pa, bv, acc[n], 0, 0, 0);
      }
    }
  }

  // epilogue: O = acc / l
  __syncthreads();
  {
    float invl[4];
#pragma unroll
    for (int i = 0; i < 4; ++i) invl[i] = 1.0f / l_s[mh * 16 + lg * 4 + i];
#pragma unroll
    for (int n = 0; n < 24; ++n) {
      int e = nh * 384 + n * 16 + l15;
#pragma unroll
      for (int i = 0; i < 4; ++i) {
        int rloc = mh * 16 + lg * 4 + i;
        Op[(size_t)rloc * DIM + e] = acc[n][i] * invl[i];
      }
    }
  }
}

// ---------------- host launcher ----------------
extern "C" void kernel_launch(void* const* d_in, const int* in_sizes, int n_in,
                              void* d_out, int out_size, void* d_ws, size_t ws_size,
                              hipStream_t stream) {
  const float* x  = (const float*)d_in[0];
  const float* Wq = (const float*)d_in[1];
  const float* Wk = (const float*)d_in[2];
  const float* Wv = (const float*)d_in[3];
  float* out = (float*)d_out;

  char* ws = (char*)d_ws;
  const size_t n_x = (size_t)BATCH * SLEN * DIM;        // 12,582,912
  unsigned short* xb = (unsigned short*)ws;                       // bf16 x
  unsigned short* wt = (unsigned short*)(ws + n_x * 2);           // 3x Wt
  unsigned short* Qw = (unsigned short*)(ws + n_x * 2 + (size_t)3 * DIM * DIM * 2);
  unsigned short* Kw = Qw + n_x;
  unsigned short* Vw = Kw + n_x;

  convert_x_kernel<<<dim3((unsigned)(n_x / 8 / 256)), 256, 0, stream>>>(x, xb);
  transpose_w_kernel<<<dim3(DIM / 32, DIM / 32, 3), 256, 0, stream>>>(Wq, Wk, Wv, wt);
  qkv_gemm_kernel<<<dim3((BATCH * SLEN) / 64, DIM / 64), 256, 0, stream>>>(xb, wt, Qw, Kw, Vw);
  attn_kernel<<<dim3(SLEN / 32, BATCH), 256, 0, stream>>>(Qw, Kw, Vw, out);
}

// Round 2
// 327.378 us; speedup vs baseline: 3.0251x; 3.0251x over previous
//
#include <hip/hip_runtime.h>
#include <hip/hip_bf16.h>
#include <hip/hip_fp16.h>

#define DIM 768
#define SLEN 4096
#define BATCH 4
#define NTILES 528  // 32*33/2 causal 128x128 tiles per batch

typedef __attribute__((ext_vector_type(8))) short short8;
typedef __attribute__((ext_vector_type(4))) short short4v;
typedef __attribute__((ext_vector_type(4))) float f32x4;
typedef __attribute__((ext_vector_type(8))) _Float16 f16x8;

typedef __attribute__((address_space(1))) void gvoid;
typedef __attribute__((address_space(3))) void lvoid;

__device__ __forceinline__ void gl_lds16(const void* g, void* l) {
  __builtin_amdgcn_global_load_lds((gvoid*)g, (lvoid*)l, 16, 0, 0);
}

__device__ __forceinline__ unsigned short f2h(float x) {
  union { _Float16 h; unsigned short u; } c; c.h = (_Float16)x; return c.u;
}
__device__ __forceinline__ float h2f(unsigned short u) {
  union { _Float16 h; unsigned short u; } c; c.u = u; return (float)c.h;
}

union V8 { short8 v; unsigned short u[8]; };

// ---------------- kernel 1: x fp32 -> fp16 ----------------
__global__ __launch_bounds__(256) void convert_x_kernel(
    const float* __restrict__ x, unsigned short* __restrict__ xb) {
  size_t i = ((size_t)blockIdx.x * 256 + threadIdx.x) * 8;
  f32x4 a = *(const f32x4*)(x + i);
  f32x4 b = *(const f32x4*)(x + i + 4);
  V8 o;
#pragma unroll
  for (int j = 0; j < 4; ++j) { o.u[j] = f2h(a[j]); o.u[4 + j] = f2h(b[j]); }
  *(short8*)(xb + i) = o.v;
}

// ---------------- kernel 2: W [k][n] fp32 -> Wt [n][k] fp16 ----------------
__global__ __launch_bounds__(256) void transpose_w_kernel(
    const float* __restrict__ Wq, const float* __restrict__ Wk,
    const float* __restrict__ Wv, unsigned short* __restrict__ Wt) {
  __shared__ float Tl[32][33];
  const float* Wi = blockIdx.z == 0 ? Wq : (blockIdx.z == 1 ? Wk : Wv);
  unsigned short* Wo = Wt + (size_t)blockIdx.z * DIM * DIM;
  int k0 = blockIdx.x * 32, n0 = blockIdx.y * 32;
  int t = threadIdx.x;
  int r = t >> 3, c4 = (t & 7) * 4;
  f32x4 v = *(const f32x4*)(Wi + (size_t)(k0 + r) * DIM + n0 + c4);
#pragma unroll
  for (int j = 0; j < 4; ++j) Tl[r][c4 + j] = v[j];
  __syncthreads();
  short4v ov;
#pragma unroll
  for (int j = 0; j < 4; ++j) ov[j] = (short)f2h(Tl[c4 + j][r]);
  *(short4v*)(Wo + (size_t)(n0 + r) * DIM + k0 + c4) = ov;
}

// ---------------- kernel 3: QKV GEMM, m97-style 128x128, BK=32 ----------------
// C[m][n] = sum_k xb[m][k] * Wt[n][k].  z=0->Q, z=1->K, z=2->Vt (transposed out).
__global__ __launch_bounds__(256) void gemm_qkv_kernel(
    const unsigned short* __restrict__ xb, const unsigned short* __restrict__ wt,
    unsigned short* __restrict__ Qo, unsigned short* __restrict__ Ko,
    unsigned short* __restrict__ Vt) {
  __shared__ __align__(16) unsigned short lds[128 * 136];  // As/Bs in loop, T in epilogue
  unsigned short* As = lds;         // [128][32]
  unsigned short* Bs = lds + 4096;  // [128][32]
  const int t = threadIdx.x, lane = t & 63, w = t >> 6;
  const int l15 = lane & 15, lg = lane >> 4;
  const int wm = w >> 1, wn = w & 1;
  const int m0 = blockIdx.x * 128, n0 = blockIdx.y * 128;
  const int z = blockIdx.z;
  const unsigned short* B = wt + (size_t)z * DIM * DIM;
  f32x4 acc[4][4];
#pragma unroll
  for (int a = 0; a < 4; ++a)
#pragma unroll
    for (int b2 = 0; b2 < 4; ++b2) acc[a][b2] = f32x4{0.f, 0.f, 0.f, 0.f};
  const int c0 = t, c1 = t + 256;
  const int r0 = c0 >> 2, k80 = (c0 & 3) * 8;
  const int r1 = c1 >> 2, k81 = (c1 & 3) * 8;

  for (int kb = 0; kb < DIM; kb += 32) {
    __syncthreads();
    gl_lds16(xb + (size_t)(m0 + r0) * DIM + kb + k80, As + (size_t)c0 * 8);
    gl_lds16(xb + (size_t)(m0 + r1) * DIM + kb + k81, As + (size_t)c1 * 8);
    gl_lds16(B + (size_t)(n0 + r0) * DIM + kb + k80, Bs + (size_t)c0 * 8);
    gl_lds16(B + (size_t)(n0 + r1) * DIM + kb + k81, Bs + (size_t)c1 * 8);
    __syncthreads();
    f16x8 a[4], bf[4];
#pragma unroll
    for (int mi = 0; mi < 4; ++mi)
      a[mi] = __builtin_bit_cast(f16x8, *(const short8*)(As + (wm * 64 + mi * 16 + l15) * 32 + lg * 8));
#pragma unroll
    for (int ni = 0; ni < 4; ++ni)
      bf[ni] = __builtin_bit_cast(f16x8, *(const short8*)(Bs + (wn * 64 + ni * 16 + l15) * 32 + lg * 8));
#pragma unroll
    for (int mi = 0; mi < 4; ++mi)
#pragma unroll
      for (int ni = 0; ni < 4; ++ni)
        acc[mi][ni] = __builtin_amdgcn_mfma_f32_16x16x32_f16(a[mi], bf[ni], acc[mi][ni], 0, 0, 0);
  }

  if (z < 2) {
    unsigned short* O = (z == 0) ? Qo : Ko;
#pragma unroll
    for (int mi = 0; mi < 4; ++mi)
#pragma unroll
      for (int ni = 0; ni < 4; ++ni)
#pragma unroll
        for (int ii = 0; ii < 4; ++ii) {
          int row = m0 + wm * 64 + mi * 16 + lg * 4 + ii;
          int col = n0 + wn * 64 + ni * 16 + l15;
          O[(size_t)row * DIM + col] = f2h(acc[mi][ni][ii]);
        }
  } else {
    // V: transpose through LDS, write Vt[b][n][s]
    __syncthreads();
    unsigned short* T = lds;  // [128][136]
#pragma unroll
    for (int mi = 0; mi < 4; ++mi)
#pragma unroll
      for (int ni = 0; ni < 4; ++ni)
#pragma unroll
        for (int ii = 0; ii < 4; ++ii) {
          int sl = wm * 64 + mi * 16 + lg * 4 + ii;
          int nl = wn * 64 + ni * 16 + l15;
          T[nl * 136 + sl] = f2h(acc[mi][ni][ii]);
        }
    __syncthreads();
    int bidx = m0 >> 12;
    int s0 = m0 & (SLEN - 1);
    unsigned short* O = Vt + (size_t)bidx * DIM * SLEN;
    int nr = t >> 1, hf = t & 1;
#pragma unroll
    for (int j = 0; j < 8; ++j)
      *(short8*)(O + (size_t)(n0 + nr) * SLEN + s0 + hf * 64 + j * 8) =
          *(const short8*)(T + nr * 136 + hf * 64 + j * 8);
  }
}

// ---------------- kernel 4: QK^T GEMM into packed causal tiles ----------------
__global__ __launch_bounds__(256) void gemm_qk_kernel(
    const unsigned short* __restrict__ Q, const unsigned short* __restrict__ K,
    unsigned short* __restrict__ S, size_t qk_bstride, size_t s_bstride) {
  __shared__ __align__(16) unsigned short As[4096], Bs[4096];
  const int i = blockIdx.x, b = blockIdx.y;
  int qt = (int)((sqrtf(8.f * i + 1.f) - 1.f) * 0.5f);
  while ((qt + 1) * (qt + 2) / 2 <= i) ++qt;
  while (qt * (qt + 1) / 2 > i) --qt;
  const int kt = i - qt * (qt + 1) / 2;
  const unsigned short* Qb = Q + (size_t)b * qk_bstride + (size_t)qt * 128 * DIM;
  const unsigned short* Kb = K + (size_t)b * qk_bstride + (size_t)kt * 128 * DIM;
  unsigned short* Sb = S + (size_t)b * s_bstride + (size_t)i * 16384;

  const int t = threadIdx.x, lane = t & 63, w = t >> 6;
  const int l15 = lane & 15, lg = lane >> 4;
  const int wm = w >> 1, wn = w & 1;
  f32x4 acc[4][4];
#pragma unroll
  for (int a = 0; a < 4; ++a)
#pragma unroll
    for (int b2 = 0; b2 < 4; ++b2) acc[a][b2] = f32x4{0.f, 0.f, 0.f, 0.f};
  const int c0 = t, c1 = t + 256;
  const int r0 = c0 >> 2, k80 = (c0 & 3) * 8;
  const int r1 = c1 >> 2, k81 = (c1 & 3) * 8;

  for (int kb = 0; kb < DIM; kb += 32) {
    __syncthreads();
    gl_lds16(Qb + (size_t)r0 * DIM + kb + k80, As + (size_t)c0 * 8);
    gl_lds16(Qb + (size_t)r1 * DIM + kb + k81, As + (size_t)c1 * 8);
    gl_lds16(Kb + (size_t)r0 * DIM + kb + k80, Bs + (size_t)c0 * 8);
    gl_lds16(Kb + (size_t)r1 * DIM + kb + k81, Bs + (size_t)c1 * 8);
    __syncthreads();
    f16x8 a[4], bf[4];
#pragma unroll
    for (int mi = 0; mi < 4; ++mi)
      a[mi] = __builtin_bit_cast(f16x8, *(const short8*)(As + (wm * 64 + mi * 16 + l15) * 32 + lg * 8));
#pragma unroll
    for (int ni = 0; ni < 4; ++ni)
      bf[ni] = __builtin_bit_cast(f16x8, *(const short8*)(Bs + (wn * 64 + ni * 16 + l15) * 32 + lg * 8));
#pragma unroll
    for (int mi = 0; mi < 4; ++mi)
#pragma unroll
      for (int ni = 0; ni < 4; ++ni)
        acc[mi][ni] = __builtin_amdgcn_mfma_f32_16x16x32_f16(a[mi], bf[ni], acc[mi][ni], 0, 0, 0);
  }
#pragma unroll
  for (int mi = 0; mi < 4; ++mi)
#pragma unroll
    for (int ni = 0; ni < 4; ++ni)
#pragma unroll
      for (int ii = 0; ii < 4; ++ii) {
        int rl = wm * 64 + mi * 16 + lg * 4 + ii;
        int cl = wn * 64 + ni * 16 + l15;
        Sb[rl * 128 + cl] = f2h(acc[mi][ni][ii]);
      }
}

// ---------------- kernel 5: row softmax (in-place, causal mask, normalize) ----------------
__global__ __launch_bounds__(256) void softmax_kernel(
    unsigned short* __restrict__ S, size_t s_bstride) {
  __shared__ float redm[4], reds[4];
  const int r = blockIdx.x, b = blockIdx.y;
  unsigned short* Sb = S + (size_t)b * s_bstride;
  const int qt = r >> 7, rl = r & 127;
  const int ncols = (qt + 1) * 128;
  const size_t rowbase = (size_t)(qt * (qt + 1) / 2) * 16384 + (size_t)rl * 128;
  const int t = threadIdx.x, lane = t & 63, w = t >> 6;
  const int c0 = t * 16;
  const bool act = c0 < ncols;
  const float NEG = -3.0e38f;
  float sv[16];
  unsigned short* p = nullptr;
  if (act) {
    int ktile = c0 >> 7, cl = c0 & 127;
    p = Sb + rowbase + (size_t)ktile * 16384 + cl;
    V8 v0, v1; v0.v = *(const short8*)p; v1.v = *(const short8*)(p + 8);
#pragma unroll
    for (int j = 0; j < 8; ++j) {
      sv[j] = (c0 + j > r) ? NEG : h2f(v0.u[j]);
      sv[8 + j] = (c0 + 8 + j > r) ? NEG : h2f(v1.u[j]);
    }
  } else {
#pragma unroll
    for (int j = 0; j < 16; ++j) sv[j] = NEG;
  }
  float mx = NEG;
#pragma unroll
  for (int j = 0; j < 16; ++j) mx = fmaxf(mx, sv[j]);
#pragma unroll
  for (int d = 1; d < 64; d <<= 1) mx = fmaxf(mx, __shfl_xor(mx, d));
  if (lane == 0) redm[w] = mx;
  __syncthreads();
  mx = fmaxf(fmaxf(redm[0], redm[1]), fmaxf(redm[2], redm[3]));

  const float scl = 1.4426950408889634f / 27.712812921102035f;  // log2(e)/sqrt(768)
  float e[16], sm = 0.f;
#pragma unroll
  for (int j = 0; j < 16; ++j) { e[j] = exp2f((sv[j] - mx) * scl); sm += e[j]; }
#pragma unroll
  for (int d = 1; d < 64; d <<= 1) sm += __shfl_xor(sm, d);
  if (lane == 0) reds[w] = sm;
  __syncthreads();
  float inv = 1.0f / (reds[0] + reds[1] + reds[2] + reds[3]);
  if (act) {
    V8 o0, o1;
#pragma unroll
    for (int j = 0; j < 8; ++j) { o0.u[j] = f2h(e[j] * inv); o1.u[j] = f2h(e[8 + j] * inv); }
    *(short8*)p = o0.v;
    *(short8*)(p + 8) = o1.v;
  }
}

// ---------------- kernel 6: PV GEMM (packed P x Vt^T -> out fp32) ----------------
__global__ __launch_bounds__(256) void gemm_pv_kernel(
    const unsigned short* __restrict__ S, const unsigned short* __restrict__ Vt,
    float* __restrict__ Out, size_t s_bstride, int nb) {
  __shared__ __align__(16) unsigned short As[4096], Bs[4096];
  const int idx = blockIdx.x;
  const int qtr = idx / (6 * nb);
  const int rem = idx - qtr * 6 * nb;
  const int b = rem / 6, nt = rem % 6;
  const int qt = 31 - qtr;  // big tiles dispatched first
  const unsigned short* Sb = S + (size_t)b * s_bstride + (size_t)(qt * (qt + 1) / 2) * 16384;
  const unsigned short* Vb = Vt + (size_t)b * DIM * SLEN + (size_t)(nt * 128) * SLEN;
  float* Ob = Out + (size_t)b * SLEN * DIM + (size_t)(qt * 128) * DIM + nt * 128;

  const int t = threadIdx.x, lane = t & 63, w = t >> 6;
  const int l15 = lane & 15, lg = lane >> 4;
  const int wm = w >> 1, wn = w & 1;
  f32x4 acc[4][4];
#pragma unroll
  for (int a = 0; a < 4; ++a)
#pragma unroll
    for (int b2 = 0; b2 < 4; ++b2) acc[a][b2] = f32x4{0.f, 0.f, 0.f, 0.f};
  const int c0 = t, c1 = t + 256;
  const int r0 = c0 >> 2, k80 = (c0 & 3) * 8;
  const int r1 = c1 >> 2, k81 = (c1 & 3) * 8;

  const int ksteps = (qt + 1) * 4;
  for (int ks = 0; ks < ksteps; ++ks) {
    const int kb = ks * 32;
    const size_t atile = (size_t)(kb >> 7) * 16384 + (size_t)(kb & 127);
    __syncthreads();
    gl_lds16(Sb + atile + (size_t)r0 * 128 + k80, As + (size_t)c0 * 8);
    gl_lds16(Sb + atile + (size_t)r1 * 128 + k81, As + (size_t)c1 * 8);
    gl_lds16(Vb + (size_t)r0 * SLEN + kb + k80, Bs + (size_t)c0 * 8);
    gl_lds16(Vb + (size_t)r1 * SLEN + kb + k81, Bs + (size_t)c1 * 8);
    __syncthreads();
    f16x8 a[4], bf[4];
#pragma unroll
    for (int mi = 0; mi < 4; ++mi)
      a[mi] = __builtin_bit_cast(f16x8, *(const short8*)(As + (wm * 64 + mi * 16 + l15) * 32 + lg * 8));
#pragma unroll
    for (int ni = 0; ni < 4; ++ni)
      bf[ni] = __builtin_bit_cast(f16x8, *(const short8*)(Bs + (wn * 64 + ni * 16 + l15) * 32 + lg * 8));
#pragma unroll
    for (int mi = 0; mi < 4; ++mi)
#pragma unroll
      for (int ni = 0; ni < 4; ++ni)
        acc[mi][ni] = __builtin_amdgcn_mfma_f32_16x16x32_f16(a[mi], bf[ni], acc[mi][ni], 0, 0, 0);
  }
#pragma unroll
  for (int mi = 0; mi < 4; ++mi)
#pragma unroll
    for (int ni = 0; ni < 4; ++ni)
#pragma unroll
      for (int ii = 0; ii < 4; ++ii) {
        int rl = wm * 64 + mi * 16 + lg * 4 + ii;
        int cl = wn * 64 + ni * 16 + l15;
        Ob[(size_t)rl * DIM + cl] = acc[mi][ni][ii];
      }
}

// ---------------- host launcher ----------------
extern "C" void kernel_launch(void* const* d_in, const int* in_sizes, int n_in,
                              void* d_out, int out_size, void* d_ws, size_t ws_size,
                              hipStream_t stream) {
  const float* x  = (const float*)d_in[0];
  const float* Wq = (const float*)d_in[1];
  const float* Wk = (const float*)d_in[2];
  const float* Wv = (const float*)d_in[3];
  float* out = (float*)d_out;

  const size_t n_x = (size_t)BATCH * SLEN * DIM;  // 12,582,912
  const size_t S_PB = (size_t)NTILES * 16384;     // 8,650,752 elems/batch
  unsigned short* Q  = (unsigned short*)d_ws;
  unsigned short* K  = Q + n_x;
  unsigned short* Vt = K + n_x;
  unsigned short* xb = Vt + n_x;
  unsigned short* wt = xb + n_x;
  const size_t base_elems = 4 * n_x + (size_t)3 * DIM * DIM;  // 52,101,120
  const bool full = ws_size >= (base_elems + 4 * S_PB) * 2;   // 173,408,256 B

  convert_x_kernel<<<dim3((unsigned)(n_x / 8 / 256)), 256, 0, stream>>>(x, xb);
  transpose_w_kernel<<<dim3(DIM / 32, DIM / 32, 3), 256, 0, stream>>>(Wq, Wk, Wv, wt);
  gemm_qkv_kernel<<<dim3((BATCH * SLEN) / 128, DIM / 128, 3), 256, 0, stream>>>(
      xb, wt, Q, K, Vt);

  if (full) {
    unsigned short* S = (unsigned short*)d_ws + base_elems;
    gemm_qk_kernel<<<dim3(NTILES, BATCH), 256, 0, stream>>>(
        Q, K, S, (size_t)SLEN * DIM, S_PB);
    softmax_kernel<<<dim3(SLEN, BATCH), 256, 0, stream>>>(S, S_PB);
    gemm_pv_kernel<<<dim3(32 * 6 * BATCH), 256, 0, stream>>>(S, Vt, out, S_PB, BATCH);
  } else {
    unsigned short* S = xb;  // overlay dead xb/wt region (28.7 MB >= 17.3 MB)
    for (int b = 0; b < BATCH; ++b) {
      const size_t qo = (size_t)b * SLEN * DIM;
      gemm_qk_kernel<<<dim3(NTILES, 1), 256, 0, stream>>>(Q + qo, K + qo, S, 0, 0);
      softmax_kernel<<<dim3(SLEN, 1), 256, 0, stream>>>(S, 0);
      gemm_pv_kernel<<<dim3(32 * 6), 256, 0, stream>>>(
          S, Vt + (size_t)b * DIM * SLEN, out + qo, 0, 1);
    }
  }
}